// Round 5
// baseline (330.069 us; speedup 1.0000x reference)
//
#include <hip/hip_runtime.h>
#include <hip/hip_bf16.h>

typedef __bf16 bf16_t;
typedef __bf16 bf16x8 __attribute__((ext_vector_type(8)));
typedef __bf16 bf16x4 __attribute__((ext_vector_type(4)));
typedef float f32x4 __attribute__((ext_vector_type(4)));
typedef unsigned int u32;

#define NUM_USER 200000
#define NUM_ITEM 200000
#define DIM_E 64
#define DIM_FEAT 128
#define HID 256
#define BATCH 16384
#define GG 17
#define NN (BATCH * GG)   // 278528
#define NREP 139264       // int(NN * 0.5)

// ---------------------------------------------------------------------------
// K1: transpose + bf16-cast weights (fragments want N-major), scatter mask
// ---------------------------------------------------------------------------
__global__ __launch_bounds__(256) void prep2_kernel(
    const float* __restrict__ W1, const float* __restrict__ W2,
    const int* __restrict__ rand_index,
    bf16_t* __restrict__ W1t, bf16_t* __restrict__ W2t,
    unsigned char* __restrict__ mask)
{
    const int t = blockIdx.x * 256 + threadIdx.x;
    if (t < HID * DIM_FEAT) {            // W1t[n][k], n<256, k<128
        const int n = t >> 7, k = t & 127;
        W1t[t] = (bf16_t)W1[k * HID + n];
    }
    if (t < DIM_E * HID) {               // W2t[n][k], n<64, k<256
        const int n = t >> 8, k = t & 255;
        W2t[t] = (bf16_t)W2[k * DIM_E + n];
    }
    if (t < NREP) mask[rand_index[t]] = 1;
}

// ---------------------------------------------------------------------------
// K2: encoder v5. One wave = 32 rows (2 strips). ZERO LDS, ZERO barriers.
//   h never leaves registers: C-layout -> B-fragment via 8 shfl + 4 selects
//   per K-step per strip (quad-dim permute within 4-lane groups).
//   W1t/W2t fragments from global (L1/L2-hot). ~120 regs -> 4 waves/SIMD.
// ---------------------------------------------------------------------------
__global__ __launch_bounds__(256, 4) void encoder5_kernel(
    const float* __restrict__ vfeat,
    const bf16_t* __restrict__ W1t, const float* __restrict__ b1v,
    const bf16_t* __restrict__ W2t, const float* __restrict__ b2v,
    bf16_t* __restrict__ featB)
{
    const int lane = threadIdx.x & 63;
    const int r    = lane & 15;          // item-row within strip
    const int Q    = lane >> 4;          // quad
    const int wid  = blockIdx.x * 4 + (threadIdx.x >> 6);
    if (wid >= 6250) return;             // 6250 * 32 == 200000 (wave-uniform exit)
    const size_t row0 = (size_t)wid * 32;

    // ---- A-phase: 2 strips of 16 v_feat rows, fused l2norm, bf16 frags ----
    bf16x8 af[2][4];
#pragma unroll
    for (int s = 0; s < 2; ++s) {
        const float* rp = vfeat + (row0 + s * 16 + r) * DIM_FEAT + Q * 8;
        float4 v0[4], v1[4];
#pragma unroll
        for (int ks = 0; ks < 4; ++ks) {
            v0[ks] = *reinterpret_cast<const float4*>(rp + ks * 32);
            v1[ks] = *reinterpret_cast<const float4*>(rp + ks * 32 + 4);
        }
        float ss = 0.f;
#pragma unroll
        for (int ks = 0; ks < 4; ++ks) {
            ss += v0[ks].x * v0[ks].x + v0[ks].y * v0[ks].y
                + v0[ks].z * v0[ks].z + v0[ks].w * v0[ks].w;
            ss += v1[ks].x * v1[ks].x + v1[ks].y * v1[ks].y
                + v1[ks].z * v1[ks].z + v1[ks].w * v1[ks].w;
        }
        ss += __shfl_xor(ss, 16, 64);
        ss += __shfl_xor(ss, 32, 64);
        const float inv = 1.0f / fmaxf(sqrtf(ss), 1e-12f);
#pragma unroll
        for (int ks = 0; ks < 4; ++ks) {
            bf16x8 v;
            v[0] = (bf16_t)(v0[ks].x * inv); v[1] = (bf16_t)(v0[ks].y * inv);
            v[2] = (bf16_t)(v0[ks].z * inv); v[3] = (bf16_t)(v0[ks].w * inv);
            v[4] = (bf16_t)(v1[ks].x * inv); v[5] = (bf16_t)(v1[ks].y * inv);
            v[6] = (bf16_t)(v1[ks].z * inv); v[7] = (bf16_t)(v1[ks].w * inv);
            af[s][ks] = v;
        }
    }

    f32x4 acc2[2][4];
#pragma unroll
    for (int s = 0; s < 2; ++s)
#pragma unroll
        for (int n2 = 0; n2 < 4; ++n2) acc2[s][n2] = (f32x4){0.f, 0.f, 0.f, 0.f};

    // shuffle source lanes for the C->B transform (within 4-lane m-groups)
    const int sl0 = (lane & 15) | ((lane & 16) << 1);  // r + 32*(Q&1)
    const int sl1 = sl0 + 16;
    const bool hiQ = (Q >= 2);

#pragma unroll
    for (int t = 0; t < 8; ++t) {
        // ---- phase 1: h-tiles 2t, 2t+1 for both strips; keep packed bf16 ----
        u32 pk[2][2][2];   // [strip][tileHalf][packedReg]  cols 4Q+{0,1}/{2,3}
#pragma unroll
        for (int h = 0; h < 2; ++h) {
            const int nt = t * 2 + h;
            const bf16_t* bp = W1t + (nt * 16 + r) * DIM_FEAT + Q * 8;
            bf16x8 w1f[4];
#pragma unroll
            for (int ks = 0; ks < 4; ++ks)
                w1f[ks] = *reinterpret_cast<const bf16x8*>(bp + ks * 32);
            const float4 bias1 = *reinterpret_cast<const float4*>(b1v + nt * 16 + Q * 4);
#pragma unroll
            for (int s = 0; s < 2; ++s) {
                f32x4 a1 = (f32x4){0.f, 0.f, 0.f, 0.f};
#pragma unroll
                for (int ks = 0; ks < 4; ++ks)   // A = W1 rows (h-cols), B = vf rows
                    a1 = __builtin_amdgcn_mfma_f32_16x16x32_bf16(w1f[ks], af[s][ks], a1, 0, 0, 0);
                bf16x4 hv4;
#pragma unroll
                for (int i = 0; i < 4; ++i) {
                    float hv = a1[i] + ((const float*)&bias1)[i];
                    hv = hv >= 0.f ? hv : 0.01f * hv;
                    hv4[i] = (bf16_t)hv;
                }
                const uint2 u = __builtin_bit_cast(uint2, hv4);
                pk[s][h][0] = u.x;   // cols 4Q+0,4Q+1 of tile nt, row r
                pk[s][h][1] = u.y;   // cols 4Q+2,4Q+3
            }
        }
        // ---- W2 fragments for k in [32t, 32t+32) ----
        bf16x8 w2f[4];
#pragma unroll
        for (int n2 = 0; n2 < 4; ++n2)
            w2f[n2] = *reinterpret_cast<const bf16x8*>(
                W2t + (n2 * 16 + r) * HID + t * 32 + Q * 8);
        // ---- transform (C-layout -> B-frag) + phase-2 MFMAs per strip ----
#pragma unroll
        for (int s = 0; s < 2; ++s) {
            const u32 q0a = (u32)__shfl((int)pk[s][0][0], sl0, 64);
            const u32 q0b = (u32)__shfl((int)pk[s][1][0], sl0, 64);
            const u32 q1a = (u32)__shfl((int)pk[s][0][1], sl0, 64);
            const u32 q1b = (u32)__shfl((int)pk[s][1][1], sl0, 64);
            const u32 q2a = (u32)__shfl((int)pk[s][0][0], sl1, 64);
            const u32 q2b = (u32)__shfl((int)pk[s][1][0], sl1, 64);
            const u32 q3a = (u32)__shfl((int)pk[s][0][1], sl1, 64);
            const u32 q3b = (u32)__shfl((int)pk[s][1][1], sl1, 64);
            uint4 bu;
            bu.x = hiQ ? q0b : q0a;
            bu.y = hiQ ? q1b : q1a;
            bu.z = hiQ ? q2b : q2a;
            bu.w = hiQ ? q3b : q3a;
            const bf16x8 hfrag = __builtin_bit_cast(bf16x8, bu);
#pragma unroll
            for (int n2 = 0; n2 < 4; ++n2)   // A = W2 rows (e-cols), B = h
                acc2[s][n2] = __builtin_amdgcn_mfma_f32_16x16x32_bf16(w2f[n2], hfrag, acc2[s][n2], 0, 0, 0);
        }
    }

    // ---- epilogue: bias + packed bf16 stores ----
#pragma unroll
    for (int n2 = 0; n2 < 4; ++n2) {
        const float4 bias2 = *reinterpret_cast<const float4*>(b2v + n2 * 16 + Q * 4);
#pragma unroll
        for (int s = 0; s < 2; ++s) {
            bf16x4 o;
            o[0] = (bf16_t)(acc2[s][n2][0] + bias2.x);
            o[1] = (bf16_t)(acc2[s][n2][1] + bias2.y);
            o[2] = (bf16_t)(acc2[s][n2][2] + bias2.z);
            o[3] = (bf16_t)(acc2[s][n2][3] + bias2.w);
            *reinterpret_cast<bf16x4*>(
                featB + (row0 + s * 16 + r) * DIM_E + n2 * 16 + Q * 4) = o;
        }
    }
}

// ---------------------------------------------------------------------------
// K3: loss elements v4 — 4-lane clusters, 2 elements/thread (MLP), bf16 f,
//     inline pos-norm (no pnrm table).
// ---------------------------------------------------------------------------
__global__ __launch_bounds__(256) void loss_elem4_kernel(
    const bf16_t* __restrict__ featB, const float* __restrict__ id_emb,
    const int* __restrict__ user_t, const int* __restrict__ item_t,
    const unsigned char* __restrict__ mask,
    float* __restrict__ s1, float* __restrict__ s2)
{
    const int kq = threadIdx.x & 3;              // dims [kq*16, kq*16+16)
    const int c  = blockIdx.x * 64 + (threadIdx.x >> 2);

#pragma unroll
    for (int half = 0; half < 2; ++half) {
        const int nn = c + half * (NN / 2);
        const int b  = nn / GG;
        const int u  = user_t[nn];
        const int it = item_t[nn];
        const int pos = item_t[b * GG];
        int fidx = min(max(it - NUM_USER, 0), NUM_ITEM - 1);
        const bool rep = mask[nn] != 0;

        const bf16x8* fp = reinterpret_cast<const bf16x8*>(featB + (size_t)fidx * DIM_E + kq * 16);
        const float4* pp = reinterpret_cast<const float4*>(id_emb + (size_t)pos * DIM_E) + kq * 4;
        const float4* up = reinterpret_cast<const float4*>(id_emb + (size_t)u   * DIM_E) + kq * 4;
        const float4* ip = reinterpret_cast<const float4*>(id_emb + (size_t)it  * DIM_E) + kq * 4;

        const bf16x8 f8a = fp[0];
        const bf16x8 f8b = fp[1];

        float x = 0.f, y = 0.f, z = 0.f, w = 0.f;
#pragma unroll
        for (int j = 0; j < 4; ++j) {
            const float4 p  = pp[j];
            const float4 uu = up[j];
            const float4 iv = ip[j];
            const bf16x8 fb = (j < 2) ? f8a : f8b;
            float f0 = (float)fb[(j & 1) * 4 + 0];
            float f1 = (float)fb[(j & 1) * 4 + 1];
            float f2 = (float)fb[(j & 1) * 4 + 2];
            float f3 = (float)fb[(j & 1) * 4 + 3];
            const float a0 = rep ? f0 : iv.x;
            const float a1 = rep ? f1 : iv.y;
            const float a2 = rep ? f2 : iv.z;
            const float a3 = rep ? f3 : iv.w;
            x += f0 * f0 + f1 * f1 + f2 * f2 + f3 * f3;
            y += p.x * p.x + p.y * p.y + p.z * p.z + p.w * p.w;
            z += p.x * f0 + p.y * f1 + p.z * f2 + p.w * f3;
            w += uu.x * a0 + uu.y * a1 + uu.z * a2 + uu.w * a3;
        }
#pragma unroll
        for (int off = 1; off <= 2; off <<= 1) {
            x += __shfl_xor(x, off, 64);
            y += __shfl_xor(y, off, 64);
            z += __shfl_xor(z, off, 64);
            w += __shfl_xor(w, off, 64);
        }
        if (kq == 0) {
            const float dot1 = z / (fmaxf(sqrtf(x), 1e-12f) * fmaxf(sqrtf(y), 1e-12f));
            s1[nn] = __expf(dot1 * 5.0f);   // 1/TEMP = 5
            s2[nn] = __expf(w * 5.0f);
        }
    }
}

// ---------------------------------------------------------------------------
// K4: per-b softmax-style loss + block reduce + single atomicAdd to d_out
// ---------------------------------------------------------------------------
__global__ __launch_bounds__(256) void loss_reduce_kernel(
    const float* __restrict__ s1, const float* __restrict__ s2,
    float* __restrict__ out)
{
    const int b = blockIdx.x * 256 + threadIdx.x;  // 64*256 == 16384 exactly
    float tot1 = 0.f, tot2 = 0.f, p1 = 0.f, p2 = 0.f;
#pragma unroll
    for (int g = 0; g < GG; ++g) {
        const float a1 = s1[b * GG + g];
        const float a2 = s2[b * GG + g];
        if (g == 0) { p1 = a1; p2 = a2; }
        tot1 += a1; tot2 += a2;
    }
    const float l1 = -logf(p1 / (tot1 + 1e-8f) + 1e-8f);
    const float l2 = -logf(p2 / (tot2 + 1e-8f) + 1e-8f);
    float v = 0.5f * l1 + 0.5f * l2;
#pragma unroll
    for (int off = 32; off > 0; off >>= 1) v += __shfl_xor(v, off, 64);
    __shared__ float red[4];
    const int wave = threadIdx.x >> 6, lane = threadIdx.x & 63;
    if (lane == 0) red[wave] = v;
    __syncthreads();
    if (threadIdx.x == 0)
        atomicAdd(out, (red[0] + red[1] + red[2] + red[3]) * (1.0f / BATCH));
}

// ---------------------------------------------------------------------------
extern "C" void kernel_launch(void* const* d_in, const int* in_sizes, int n_in,
                              void* d_out, int out_size, void* d_ws, size_t ws_size,
                              hipStream_t stream)
{
    (void)in_sizes; (void)n_in; (void)out_size; (void)ws_size;
    const float* v_feat    = (const float*)d_in[0];
    const float* id_emb    = (const float*)d_in[1];
    const float* W1        = (const float*)d_in[2];
    const float* b1        = (const float*)d_in[3];
    const float* W2        = (const float*)d_in[4];
    const float* b2        = (const float*)d_in[5];
    const int*   user_t    = (const int*)d_in[6];
    const int*   item_t    = (const int*)d_in[7];
    const int*   rand_idx  = (const int*)d_in[8];

    char* ws = (char*)d_ws;
    bf16_t*        W1t      = (bf16_t*)(ws + 0);             // 65536
    bf16_t*        W2t      = (bf16_t*)(ws + 65536);         // 32768
    unsigned char* mask     = (unsigned char*)(ws + 98304);  // 278528
    float*         s1       = (float*)(ws + 376832);         // 1114112
    float*         s2       = (float*)(ws + 1490944);        // 1114112
    bf16_t*        featB    = (bf16_t*)(ws + 2605056);       // 25600000

    hipMemsetAsync(mask, 0, NN, stream);
    hipMemsetAsync(d_out, 0, sizeof(float), stream);
    prep2_kernel<<<544, 256, 0, stream>>>(W1, W2, rand_idx, W1t, W2t, mask);
    encoder5_kernel<<<1563, 256, 0, stream>>>(v_feat, W1t, b1, W2t, b2, featB);
    loss_elem4_kernel<<<2176, 256, 0, stream>>>(featB, id_emb, user_t, item_t, mask, s1, s2);
    loss_reduce_kernel<<<64, 256, 0, stream>>>(s1, s2, (float*)d_out);
}

// Round 6
// 281.809 us; speedup vs baseline: 1.1713x; 1.1713x over previous
//
#include <hip/hip_runtime.h>
#include <hip/hip_bf16.h>

typedef __bf16 bf16_t;
typedef __bf16 bf16x8 __attribute__((ext_vector_type(8)));
typedef __bf16 bf16x4 __attribute__((ext_vector_type(4)));
typedef float f32x4 __attribute__((ext_vector_type(4)));
typedef unsigned int u32;

#define NUM_USER 200000
#define NUM_ITEM 200000
#define DIM_E 64
#define DIM_FEAT 128
#define HID 256
#define BATCH 16384
#define GG 17
#define NN (BATCH * GG)   // 278528
#define NREP 139264       // int(NN * 0.5)
#define W1LP 136          // W1 LDS pitch (bf16): 68 words -> bank shift 4/row
#define W2LP 264          // W2 LDS pitch (bf16): 132 words -> bank shift 4/row
#define NWAVES 2048       // 256 blocks x 8 waves
#define NSP 6250          // strip-pairs: 6250 * 32 == 200000

// ---------------------------------------------------------------------------
// K1: transpose + bf16-cast weights (fragments want N-major), scatter mask
// ---------------------------------------------------------------------------
__global__ __launch_bounds__(256) void prep2_kernel(
    const float* __restrict__ W1, const float* __restrict__ W2,
    const int* __restrict__ rand_index,
    bf16_t* __restrict__ W1t, bf16_t* __restrict__ W2t,
    unsigned char* __restrict__ mask)
{
    const int t = blockIdx.x * 256 + threadIdx.x;
    if (t < HID * DIM_FEAT) {            // W1t[n][k], n<256, k<128
        const int n = t >> 7, k = t & 127;
        W1t[t] = (bf16_t)W1[k * HID + n];
    }
    if (t < DIM_E * HID) {               // W2t[n][k], n<64, k<256
        const int n = t >> 8, k = t & 255;
        W2t[t] = (bf16_t)W2[k * DIM_E + n];
    }
    if (t < NREP) mask[rand_index[t]] = 1;
}

// ---------------------------------------------------------------------------
// K2: encoder v6. Weights LDS-resident for the block lifetime (one barrier).
//   Per-wave strip loop: 32 rows/iter, v_feat prefetched one strip ahead,
//   inner loop touches ONLY LDS + MFMA + shuffle transform (v5-proven).
// ---------------------------------------------------------------------------
__global__ __launch_bounds__(512, 2) void encoder6_kernel(
    const float* __restrict__ vfeat,
    const bf16_t* __restrict__ W1t, const float* __restrict__ b1v,
    const bf16_t* __restrict__ W2t, const float* __restrict__ b2v,
    bf16_t* __restrict__ featB)
{
    const int tid  = threadIdx.x;
    const int wave = tid >> 6;
    const int lane = tid & 63;
    const int r    = lane & 15;          // item-row within strip
    const int Q    = lane >> 4;          // quad

    __shared__ bf16_t w1s[256 * W1LP];   // 69632 B
    __shared__ bf16_t w2s[64 * W2LP];    // 33792 B
    __shared__ float  b1s[HID];
    __shared__ float  b2s[DIM_E];

    // ---- stage weights once ----
    for (int c = tid; c < 4096; c += 512) {        // W1t: 4096 uint4
        const int n = c >> 4, ks = c & 15;
        *reinterpret_cast<uint4*>(&w1s[n * W1LP + ks * 8]) =
            reinterpret_cast<const uint4*>(W1t)[c];
    }
    for (int c = tid; c < 2048; c += 512) {        // W2t: 2048 uint4
        const int n = c >> 5, ks = c & 31;
        *reinterpret_cast<uint4*>(&w2s[n * W2LP + ks * 8]) =
            reinterpret_cast<const uint4*>(W2t)[c];
    }
    if (tid < HID) b1s[tid] = b1v[tid];
    if (tid < DIM_E) b2s[tid] = b2v[tid];
    __syncthreads();                                // the only barrier

    // shuffle-transform lane map (within 4-lane m-groups)
    const int sl0 = r + ((lane & 16) << 1);
    const int sl1 = sl0 + 16;
    const bool hiQ = (Q >= 2);

    int sp = blockIdx.x * 8 + wave;                 // strip-pair id

    float4 v0[2][4], v1[2][4];
    // initial prefetch
    {
        const size_t row0 = (size_t)sp * 32;
#pragma unroll
        for (int s = 0; s < 2; ++s) {
            const float* rp = vfeat + (row0 + s * 16 + r) * DIM_FEAT + Q * 8;
#pragma unroll
            for (int ks = 0; ks < 4; ++ks) {
                v0[s][ks] = *reinterpret_cast<const float4*>(rp + ks * 32);
                v1[s][ks] = *reinterpret_cast<const float4*>(rp + ks * 32 + 4);
            }
        }
    }

    while (sp < NSP) {
        const size_t row0 = (size_t)sp * 32;

        // ---- build normalized bf16 A-fragments from prefetched regs ----
        bf16x8 af[2][4];
#pragma unroll
        for (int s = 0; s < 2; ++s) {
            float ss = 0.f;
#pragma unroll
            for (int ks = 0; ks < 4; ++ks) {
                ss += v0[s][ks].x * v0[s][ks].x + v0[s][ks].y * v0[s][ks].y
                    + v0[s][ks].z * v0[s][ks].z + v0[s][ks].w * v0[s][ks].w;
                ss += v1[s][ks].x * v1[s][ks].x + v1[s][ks].y * v1[s][ks].y
                    + v1[s][ks].z * v1[s][ks].z + v1[s][ks].w * v1[s][ks].w;
            }
            ss += __shfl_xor(ss, 16, 64);
            ss += __shfl_xor(ss, 32, 64);
            const float inv = 1.0f / fmaxf(sqrtf(ss), 1e-12f);
#pragma unroll
            for (int ks = 0; ks < 4; ++ks) {
                bf16x8 v;
                v[0] = (bf16_t)(v0[s][ks].x * inv); v[1] = (bf16_t)(v0[s][ks].y * inv);
                v[2] = (bf16_t)(v0[s][ks].z * inv); v[3] = (bf16_t)(v0[s][ks].w * inv);
                v[4] = (bf16_t)(v1[s][ks].x * inv); v[5] = (bf16_t)(v1[s][ks].y * inv);
                v[6] = (bf16_t)(v1[s][ks].z * inv); v[7] = (bf16_t)(v1[s][ks].w * inv);
                af[s][ks] = v;
            }
        }

        // ---- prefetch next strip (latency hides under t-loop) ----
        const int spn = sp + NWAVES;
        if (spn < NSP) {
            const size_t nr0 = (size_t)spn * 32;
#pragma unroll
            for (int s = 0; s < 2; ++s) {
                const float* rp = vfeat + (nr0 + s * 16 + r) * DIM_FEAT + Q * 8;
#pragma unroll
                for (int ks = 0; ks < 4; ++ks) {
                    v0[s][ks] = *reinterpret_cast<const float4*>(rp + ks * 32);
                    v1[s][ks] = *reinterpret_cast<const float4*>(rp + ks * 32 + 4);
                }
            }
        }

        f32x4 acc2[2][4];
#pragma unroll
        for (int s = 0; s < 2; ++s)
#pragma unroll
            for (int n2 = 0; n2 < 4; ++n2) acc2[s][n2] = (f32x4){0.f, 0.f, 0.f, 0.f};

#pragma unroll 2
        for (int t = 0; t < 8; ++t) {
            // ---- phase 1: h-tiles 2t, 2t+1 (both strips), from LDS W1 ----
            u32 pk[2][2][2];   // [strip][tileHalf][reg]
#pragma unroll
            for (int h = 0; h < 2; ++h) {
                const int nt = t * 2 + h;
                const bf16_t* bp = &w1s[(nt * 16 + r) * W1LP + Q * 8];
                bf16x8 w1f[4];
#pragma unroll
                for (int ks = 0; ks < 4; ++ks)
                    w1f[ks] = *reinterpret_cast<const bf16x8*>(bp + ks * 32);
                const float4 bias1 = *reinterpret_cast<const float4*>(&b1s[nt * 16 + Q * 4]);
#pragma unroll
                for (int s = 0; s < 2; ++s) {
                    f32x4 a1 = (f32x4){0.f, 0.f, 0.f, 0.f};
#pragma unroll
                    for (int ks = 0; ks < 4; ++ks)
                        a1 = __builtin_amdgcn_mfma_f32_16x16x32_bf16(w1f[ks], af[s][ks], a1, 0, 0, 0);
                    bf16x4 hv4;
#pragma unroll
                    for (int i = 0; i < 4; ++i) {
                        float hv = a1[i] + ((const float*)&bias1)[i];
                        hv = hv >= 0.f ? hv : 0.01f * hv;
                        hv4[i] = (bf16_t)hv;
                    }
                    const uint2 u = __builtin_bit_cast(uint2, hv4);
                    pk[s][h][0] = u.x;
                    pk[s][h][1] = u.y;
                }
            }
            // ---- W2 fragments for k in [32t, 32t+32) from LDS ----
            bf16x8 w2f[4];
#pragma unroll
            for (int n2 = 0; n2 < 4; ++n2)
                w2f[n2] = *reinterpret_cast<const bf16x8*>(
                    &w2s[(n2 * 16 + r) * W2LP + t * 32 + Q * 8]);
            // ---- C->B transform + phase-2 MFMAs ----
#pragma unroll
            for (int s = 0; s < 2; ++s) {
                const u32 q0a = (u32)__shfl((int)pk[s][0][0], sl0, 64);
                const u32 q0b = (u32)__shfl((int)pk[s][1][0], sl0, 64);
                const u32 q1a = (u32)__shfl((int)pk[s][0][1], sl0, 64);
                const u32 q1b = (u32)__shfl((int)pk[s][1][1], sl0, 64);
                const u32 q2a = (u32)__shfl((int)pk[s][0][0], sl1, 64);
                const u32 q2b = (u32)__shfl((int)pk[s][1][0], sl1, 64);
                const u32 q3a = (u32)__shfl((int)pk[s][0][1], sl1, 64);
                const u32 q3b = (u32)__shfl((int)pk[s][1][1], sl1, 64);
                uint4 bu;
                bu.x = hiQ ? q0b : q0a;
                bu.y = hiQ ? q1b : q1a;
                bu.z = hiQ ? q2b : q2a;
                bu.w = hiQ ? q3b : q3a;
                const bf16x8 hfrag = __builtin_bit_cast(bf16x8, bu);
#pragma unroll
                for (int n2 = 0; n2 < 4; ++n2)
                    acc2[s][n2] = __builtin_amdgcn_mfma_f32_16x16x32_bf16(w2f[n2], hfrag, acc2[s][n2], 0, 0, 0);
            }
        }

        // ---- epilogue: bias + packed bf16 stores ----
#pragma unroll
        for (int n2 = 0; n2 < 4; ++n2) {
            const float4 bias2 = *reinterpret_cast<const float4*>(&b2s[n2 * 16 + Q * 4]);
#pragma unroll
            for (int s = 0; s < 2; ++s) {
                bf16x4 o;
                o[0] = (bf16_t)(acc2[s][n2][0] + bias2.x);
                o[1] = (bf16_t)(acc2[s][n2][1] + bias2.y);
                o[2] = (bf16_t)(acc2[s][n2][2] + bias2.z);
                o[3] = (bf16_t)(acc2[s][n2][3] + bias2.w);
                *reinterpret_cast<bf16x4*>(
                    featB + (row0 + s * 16 + r) * DIM_E + n2 * 16 + Q * 4) = o;
            }
        }
        sp = spn;
    }
}

// ---------------------------------------------------------------------------
// K3: loss elements — 4-lane clusters, 2 elements/thread, bf16 feature
// ---------------------------------------------------------------------------
__global__ __launch_bounds__(256) void loss_elem4_kernel(
    const bf16_t* __restrict__ featB, const float* __restrict__ id_emb,
    const int* __restrict__ user_t, const int* __restrict__ item_t,
    const unsigned char* __restrict__ mask,
    float* __restrict__ s1, float* __restrict__ s2)
{
    const int kq = threadIdx.x & 3;              // dims [kq*16, kq*16+16)
    const int c  = blockIdx.x * 64 + (threadIdx.x >> 2);

#pragma unroll
    for (int half = 0; half < 2; ++half) {
        const int nn = c + half * (NN / 2);
        const int b  = nn / GG;
        const int u  = user_t[nn];
        const int it = item_t[nn];
        const int pos = item_t[b * GG];
        int fidx = min(max(it - NUM_USER, 0), NUM_ITEM - 1);
        const bool rep = mask[nn] != 0;

        const bf16x8* fp = reinterpret_cast<const bf16x8*>(featB + (size_t)fidx * DIM_E + kq * 16);
        const float4* pp = reinterpret_cast<const float4*>(id_emb + (size_t)pos * DIM_E) + kq * 4;
        const float4* up = reinterpret_cast<const float4*>(id_emb + (size_t)u   * DIM_E) + kq * 4;
        const float4* ip = reinterpret_cast<const float4*>(id_emb + (size_t)it  * DIM_E) + kq * 4;

        const bf16x8 f8a = fp[0];
        const bf16x8 f8b = fp[1];

        float x = 0.f, y = 0.f, z = 0.f, w = 0.f;
#pragma unroll
        for (int j = 0; j < 4; ++j) {
            const float4 p  = pp[j];
            const float4 uu = up[j];
            const float4 iv = ip[j];
            const bf16x8 fb = (j < 2) ? f8a : f8b;
            float f0 = (float)fb[(j & 1) * 4 + 0];
            float f1 = (float)fb[(j & 1) * 4 + 1];
            float f2 = (float)fb[(j & 1) * 4 + 2];
            float f3 = (float)fb[(j & 1) * 4 + 3];
            const float a0 = rep ? f0 : iv.x;
            const float a1 = rep ? f1 : iv.y;
            const float a2 = rep ? f2 : iv.z;
            const float a3 = rep ? f3 : iv.w;
            x += f0 * f0 + f1 * f1 + f2 * f2 + f3 * f3;
            y += p.x * p.x + p.y * p.y + p.z * p.z + p.w * p.w;
            z += p.x * f0 + p.y * f1 + p.z * f2 + p.w * f3;
            w += uu.x * a0 + uu.y * a1 + uu.z * a2 + uu.w * a3;
        }
#pragma unroll
        for (int off = 1; off <= 2; off <<= 1) {
            x += __shfl_xor(x, off, 64);
            y += __shfl_xor(y, off, 64);
            z += __shfl_xor(z, off, 64);
            w += __shfl_xor(w, off, 64);
        }
        if (kq == 0) {
            const float dot1 = z / (fmaxf(sqrtf(x), 1e-12f) * fmaxf(sqrtf(y), 1e-12f));
            s1[nn] = __expf(dot1 * 5.0f);   // 1/TEMP = 5
            s2[nn] = __expf(w * 5.0f);
        }
    }
}

// ---------------------------------------------------------------------------
// K4: per-b softmax-style loss + block reduce + single atomicAdd to d_out
// ---------------------------------------------------------------------------
__global__ __launch_bounds__(256) void loss_reduce_kernel(
    const float* __restrict__ s1, const float* __restrict__ s2,
    float* __restrict__ out)
{
    const int b = blockIdx.x * 256 + threadIdx.x;  // 64*256 == 16384 exactly
    float tot1 = 0.f, tot2 = 0.f, p1 = 0.f, p2 = 0.f;
#pragma unroll
    for (int g = 0; g < GG; ++g) {
        const float a1 = s1[b * GG + g];
        const float a2 = s2[b * GG + g];
        if (g == 0) { p1 = a1; p2 = a2; }
        tot1 += a1; tot2 += a2;
    }
    const float l1 = -logf(p1 / (tot1 + 1e-8f) + 1e-8f);
    const float l2 = -logf(p2 / (tot2 + 1e-8f) + 1e-8f);
    float v = 0.5f * l1 + 0.5f * l2;
#pragma unroll
    for (int off = 32; off > 0; off >>= 1) v += __shfl_xor(v, off, 64);
    __shared__ float red[4];
    const int wave = threadIdx.x >> 6, lane = threadIdx.x & 63;
    if (lane == 0) red[wave] = v;
    __syncthreads();
    if (threadIdx.x == 0)
        atomicAdd(out, (red[0] + red[1] + red[2] + red[3]) * (1.0f / BATCH));
}

// ---------------------------------------------------------------------------
extern "C" void kernel_launch(void* const* d_in, const int* in_sizes, int n_in,
                              void* d_out, int out_size, void* d_ws, size_t ws_size,
                              hipStream_t stream)
{
    (void)in_sizes; (void)n_in; (void)out_size; (void)ws_size;
    const float* v_feat    = (const float*)d_in[0];
    const float* id_emb    = (const float*)d_in[1];
    const float* W1        = (const float*)d_in[2];
    const float* b1        = (const float*)d_in[3];
    const float* W2        = (const float*)d_in[4];
    const float* b2        = (const float*)d_in[5];
    const int*   user_t    = (const int*)d_in[6];
    const int*   item_t    = (const int*)d_in[7];
    const int*   rand_idx  = (const int*)d_in[8];

    char* ws = (char*)d_ws;
    bf16_t*        W1t      = (bf16_t*)(ws + 0);             // 65536
    bf16_t*        W2t      = (bf16_t*)(ws + 65536);         // 32768
    unsigned char* mask     = (unsigned char*)(ws + 98304);  // 278528
    float*         s1       = (float*)(ws + 376832);         // 1114112
    float*         s2       = (float*)(ws + 1490944);        // 1114112
    bf16_t*        featB    = (bf16_t*)(ws + 2605056);       // 25600000

    hipMemsetAsync(mask, 0, NN, stream);
    hipMemsetAsync(d_out, 0, sizeof(float), stream);
    prep2_kernel<<<544, 256, 0, stream>>>(W1, W2, rand_idx, W1t, W2t, mask);
    encoder6_kernel<<<256, 512, 0, stream>>>(v_feat, W1t, b1, W2t, b2, featB);
    loss_elem4_kernel<<<2176, 256, 0, stream>>>(featB, id_emb, user_t, item_t, mask, s1, s2);
    loss_reduce_kernel<<<64, 256, 0, stream>>>(s1, s2, (float*)d_out);
}